// Round 2
// baseline (885.052 us; speedup 1.0000x reference)
//
#include <hip/hip_runtime.h>
#include <math.h>

// ---------------- workspace layout (floats) ----------------
#define WS_W12   0                         // [9*9][32]       = 2592
#define WS_B12   2592                      // 32
#define WS_W34   2624                      // [32][9][9][64]  = 165888
#define WS_B34   (2624 + 165888)           // 64
#define WS_P1    (WS_B34 + 64)             // [64][30][30][32] = 1843200 (oc innermost!)
#define WS_EMB   (WS_P1 + 64*30*30*32)     // [64][1600]       = 102400
#define WS_LOG   (WS_EMB + 64*1600)        // [64][3]

// ---------------- kernel A1: compose conv1*conv2 -> 9x9, 1->32ch ----------
// grid = 32 (one per oc), block = 128. Weights staged in LDS, coalesced.
__global__ __launch_bounds__(128) void k_prep12(
    const float* __restrict__ w1, const float* __restrict__ b1,
    const float* __restrict__ w2, const float* __restrict__ b2,
    float* __restrict__ W12, float* __restrict__ B12)
{
    __shared__ float sW2[800];   // w2[oc][mc][e], mc*25+e
    __shared__ float sW1[800];   // w1[mc][e]
    int oc = blockIdx.x;
    int t  = threadIdx.x;
    for (int i = t; i < 800; i += 128) {
        sW2[i] = w2[oc * 800 + i];
        sW1[i] = w1[i];
    }
    __syncthreads();

    for (int uv = t; uv < 81; uv += 128) {
        int u = uv / 9, v = uv % 9;
        int ey0 = max(0, u - 4), ey1 = min(4, u);
        int ex0 = max(0, v - 4), ex1 = min(4, v);
        float s = 0.f;
        for (int mc = 0; mc < 32; ++mc) {
            const float* w2r = &sW2[mc * 25];
            const float* w1r = &sW1[mc * 25];
            for (int ey = ey0; ey <= ey1; ++ey)
                for (int ex = ex0; ex <= ex1; ++ex)
                    s += w2r[ey * 5 + ex] * w1r[(u - ey) * 5 + (v - ex)];
        }
        W12[uv * 32 + oc] = s;
    }
    if (t == 0) {
        float s = b2[oc];
        for (int mc = 0; mc < 32; ++mc) {
            float ws = 0.f;
            for (int e = 0; e < 25; ++e) ws += sW2[mc * 25 + e];
            s += b1[mc] * ws;
        }
        B12[oc] = s;
    }
}

// ---------------- kernel A2: compose conv3*conv4 -> 9x9, 32->64ch ---------
// grid = 256: blockIdx = oc*4 + icg (ic-group of 8). LDS-staged, coalesced.
__global__ __launch_bounds__(256) void k_prep34(
    const float* __restrict__ w3, const float* __restrict__ b3,
    const float* __restrict__ w4, const float* __restrict__ b4,
    float* __restrict__ W34, float* __restrict__ B34)
{
    __shared__ float sW4[64 * 25];        // w4[oc][mc][e]           6.4 KB
    __shared__ float sW3[64 * 200];       // w3[mc][ic in grp][e]   51.2 KB
    int oc  = blockIdx.x >> 2;
    int icg = blockIdx.x & 3;
    int t   = threadIdx.x;

    for (int i = t; i < 1600; i += 256) sW4[i] = w4[oc * 1600 + i];
    for (int i = t; i < 64 * 200; i += 256) {
        int mc = i / 200, r = i % 200;
        sW3[i] = w3[mc * 800 + icg * 200 + r];
    }
    __syncthreads();

    for (int o = t; o < 648; o += 256) {
        int icl = o / 81;                 // 0..7 local ic
        int uv  = o % 81;
        int u = uv / 9, v = uv % 9;
        int ey0 = max(0, u - 4), ey1 = min(4, u);
        int ex0 = max(0, v - 4), ex1 = min(4, v);
        float s = 0.f;
        for (int mc = 0; mc < 64; ++mc) {
            const float* w4r = &sW4[mc * 25];
            const float* w3r = &sW3[mc * 200 + icl * 25];
            for (int ey = ey0; ey <= ey1; ++ey)
                for (int ex = ex0; ex <= ex1; ++ex)
                    s += w4r[ey * 5 + ex] * w3r[(u - ey) * 5 + (v - ex)];
        }
        int ic = icg * 8 + icl;
        W34[((ic * 9 + u) * 9 + v) * 64 + oc] = s;
    }
    if (icg == 0 && t == 0) {
        float s = b4[oc];
        for (int mc = 0; mc < 64; ++mc) {
            float ws = 0.f;
            for (int e = 0; e < 25; ++e) ws += sW4[mc * 25 + e];
            s += b3[mc] * ws;
        }
        B34[oc] = s;
    }
}

// ---------------- kernel B: fused 9x9 conv12 + 4x4 maxpool ----------------
// grid = 64 batches * 30 pool-rows; block = 256 = 32 oc * 8 px-groups.
// Weights in registers (81), sliding-row structure: each input row read once.
__global__ __launch_bounds__(256) void k_conv12(
    const float* __restrict__ x, const float* __restrict__ W12,
    const float* __restrict__ B12, float* __restrict__ P1)
{
    __shared__ float sIn[12][128];     // input rows 4py..4py+11

    int b  = blockIdx.x / 30;
    int py = blockIdx.x % 30;
    int t  = threadIdx.x;

    const float* xb = x + b * 128 * 128;
    for (int i = t; i < 12 * 32; i += 256) {          // 384 float4
        int row = i >> 5, c4 = i & 31;
        ((float4*)sIn[row])[c4] =
            ((const float4*)(xb + (4 * py + row) * 128))[c4];
    }

    int oc = t & 31;
    int pg = t >> 5;                                  // 0..7
    float w[81];
    #pragma unroll
    for (int e = 0; e < 81; ++e) w[e] = W12[e * 32 + oc];   // coalesced, L2
    float bias = B12[oc];
    __syncthreads();

    for (int j = 0; j < 4; ++j) {
        int px = pg + 8 * j;
        if (px >= 30) break;                          // wave-uniform
        float acc[4][4];
        #pragma unroll
        for (int iy = 0; iy < 4; ++iy)
            #pragma unroll
            for (int ix = 0; ix < 4; ++ix) acc[iy][ix] = 0.f;

        #pragma unroll
        for (int r = 0; r < 12; ++r) {                // each row read ONCE
            const float* rp = sIn[r] + 4 * px;
            float4 A  = ((const float4*)rp)[0];
            float4 Bq = ((const float4*)rp)[1];
            float4 Cq = ((const float4*)rp)[2];
            float win[12] = {A.x, A.y, A.z, A.w, Bq.x, Bq.y, Bq.z, Bq.w,
                             Cq.x, Cq.y, Cq.z, Cq.w};
            #pragma unroll
            for (int iy = 0; iy < 4; ++iy) {
                int ky = r - iy;                      // compile-time after unroll
                if (ky < 0 || ky > 8) continue;
                #pragma unroll
                for (int ix = 0; ix < 4; ++ix)
                    #pragma unroll
                    for (int kx = 0; kx < 9; ++kx)
                        acc[iy][ix] = fmaf(w[ky * 9 + kx], win[ix + kx],
                                           acc[iy][ix]);
            }
        }
        float m = -INFINITY;
        #pragma unroll
        for (int iy = 0; iy < 4; ++iy)
            #pragma unroll
            for (int ix = 0; ix < 4; ++ix) m = fmaxf(m, acc[iy][ix]);
        // oc-innermost layout: coalesced wave store
        P1[((b * 30 + py) * 30 + px) * 32 + oc] = m + bias;
    }
}

// ---------------- kernel C: fused 9x9 conv34 + 4x4 maxpool ----------------
// grid = 64 b * 5 py * 2 oc-halves = 640; block = 320 = 32 oc * 10 grp
__global__ __launch_bounds__(320) void k_conv34(
    const float* __restrict__ P1, const float* __restrict__ W34,
    const float* __restrict__ B34, float* __restrict__ emb)
{
    __shared__ float sIn[32][12][32];   // [ic][row][col] (30 used of 32)
    __shared__ float sPool[10][32];

    int bi  = blockIdx.x;
    int b   = bi / 10;
    int rem = bi % 10;
    int py  = rem >> 1;
    int oh  = rem & 1;
    int t   = threadIdx.x;

    // P1 is ic-innermost: consecutive lanes -> consecutive addresses
    for (int i = t; i < 32 * 12 * 30; i += 320) {
        int ic  = i & 31;
        int rc  = i >> 5;                 // 0..359
        int row = rc / 30, col = rc % 30;
        sIn[ic][row][col] = P1[((b * 30 + 4 * py + row) * 30 + col) * 32 + ic];
    }
    __syncthreads();

    int ocl  = t & 31;
    int oc   = ocl + (oh << 5);
    int grp  = t >> 5;          // 0..9
    int iyh  = grp / 5;         // iy in {2iyh, 2iyh+1}
    int cgrp = grp % 5;         // pool col

    float acc[2][4];
    #pragma unroll
    for (int d = 0; d < 2; ++d)
        #pragma unroll
        for (int ix = 0; ix < 4; ++ix) acc[d][ix] = 0.f;

    for (int ic = 0; ic < 32; ++ic) {
        for (int ky = 0; ky < 9; ++ky) {
            float w[9];
            #pragma unroll
            for (int kx = 0; kx < 9; ++kx)
                w[kx] = W34[((ic * 9 + ky) * 9 + kx) * 64 + oc];
            #pragma unroll
            for (int d = 0; d < 2; ++d) {
                int row = 2 * iyh + d + ky;
                const float* rp = &sIn[ic][row][4 * cgrp];
                float4 A  = ((const float4*)rp)[0];
                float4 Bq = ((const float4*)rp)[1];
                float4 Cq = ((const float4*)rp)[2];
                float win[12] = {A.x, A.y, A.z, A.w, Bq.x, Bq.y, Bq.z, Bq.w,
                                 Cq.x, Cq.y, Cq.z, Cq.w};
                #pragma unroll
                for (int ix = 0; ix < 4; ++ix)
                    #pragma unroll
                    for (int kx = 0; kx < 9; ++kx)
                        acc[d][ix] = fmaf(w[kx], win[ix + kx], acc[d][ix]);
            }
        }
    }

    float pmax = -INFINITY;
    #pragma unroll
    for (int d = 0; d < 2; ++d)
        #pragma unroll
        for (int ix = 0; ix < 4; ++ix) pmax = fmaxf(pmax, acc[d][ix]);
    sPool[grp][ocl] = pmax;
    __syncthreads();

    if (grp < 5) {
        float m = fmaxf(sPool[grp][ocl], sPool[grp + 5][ocl]) + B34[oc];
        emb[b * 1600 + oc * 25 + py * 5 + grp] = m;   // [b][oc*25+y*5+x]
    }
}

// ---------------- kernel D: FC heads (only needed output columns) ---------
__device__ __forceinline__ float block_sum256(float v, float* sred, int t) {
    #pragma unroll
    for (int o = 32; o; o >>= 1) v += __shfl_down(v, o, 64);
    __syncthreads();
    if ((t & 63) == 0) sred[t >> 6] = v;
    __syncthreads();
    return sred[0] + sred[1] + sred[2] + sred[3];
}

// grid = 128: blockIdx>>6 = head (0:edge,1:endpoint), blockIdx&63 = batch
__global__ __launch_bounds__(256) void k_fc(
    const float* __restrict__ emb,
    const float* __restrict__ w_ed1, const float* __restrict__ b_ed1,
    const float* __restrict__ w_ed2, const float* __restrict__ b_ed2,
    const float* __restrict__ w_ep1, const float* __restrict__ b_ep1,
    const float* __restrict__ w_ep2, const float* __restrict__ b_ep2,
    const int* __restrict__ esrc, const int* __restrict__ edst,
    float* __restrict__ logits)
{
    __shared__ float se[1600];
    __shared__ float sred[4];

    int head = blockIdx.x >> 6;
    int b    = blockIdx.x & 63;
    int j    = threadIdx.x;     // hidden unit

    const float* W1 = head ? w_ep1 : w_ed1;
    const float* B1 = head ? b_ep1 : b_ed1;

    for (int i = j; i < 1600; i += 256) se[i] = emb[b * 1600 + i];
    __syncthreads();

    float s = B1[j];
    for (int k = 0; k < 1600; ++k) s = fmaf(se[k], W1[k * 256 + j], s);
    float h = fmaxf(s, 0.f);

    if (head == 0) {
        float p = h * w_ed2[j * 120 + 0];
        float tot = block_sum256(p, sred, j);
        if (j == 0) logits[b * 3 + 0] = tot + b_ed2[0];
    } else {
        int c0 = esrc[0];
        int c1 = edst[0];
        float p0 = h * w_ep2[j * 36 + c0];
        float p1 = h * w_ep2[j * 36 + c1];
        float t0 = block_sum256(p0, sred, j);
        float t1 = block_sum256(p1, sred, j);
        if (j == 0) {
            logits[b * 3 + 1] = t0 + b_ep2[c0];
            logits[b * 3 + 2] = t1 + b_ep2[c1];
        }
    }
}

// ---------------- kernel E: sigmoid products -> out ----------------------
__global__ __launch_bounds__(64) void k_final(
    const float* __restrict__ logits, float* __restrict__ out)
{
    int b = threadIdx.x;
    if (b < 64) {
        float e  = logits[b * 3 + 0];
        float p0 = logits[b * 3 + 1];
        float p1 = logits[b * 3 + 2];
        float se  = 1.f / (1.f + expf(-e));
        float sp0 = 1.f / (1.f + expf(-p0));
        float sp1 = 1.f / (1.f + expf(-p1));
        out[b] = se * sp0 * sp1;
    }
}

// ---------------- launch --------------------------------------------------
extern "C" void kernel_launch(void* const* d_in, const int* in_sizes, int n_in,
                              void* d_out, int out_size, void* d_ws, size_t ws_size,
                              hipStream_t stream)
{
    const float* x     = (const float*)d_in[0];
    const float* w1    = (const float*)d_in[1];
    const float* b1    = (const float*)d_in[2];
    const float* w2    = (const float*)d_in[3];
    const float* b2    = (const float*)d_in[4];
    const float* w3    = (const float*)d_in[5];
    const float* b3    = (const float*)d_in[6];
    const float* w4    = (const float*)d_in[7];
    const float* b4    = (const float*)d_in[8];
    const float* w_ed1 = (const float*)d_in[9];
    const float* b_ed1 = (const float*)d_in[10];
    const float* w_ed2 = (const float*)d_in[11];
    const float* b_ed2 = (const float*)d_in[12];
    const float* w_ep1 = (const float*)d_in[13];
    const float* b_ep1 = (const float*)d_in[14];
    const float* w_ep2 = (const float*)d_in[15];
    const float* b_ep2 = (const float*)d_in[16];
    const int*   esrc  = (const int*)d_in[17];
    const int*   edst  = (const int*)d_in[18];

    float* ws  = (float*)d_ws;
    float* out = (float*)d_out;

    k_prep12<<<32, 128, 0, stream>>>(w1, b1, w2, b2, ws + WS_W12, ws + WS_B12);
    k_prep34<<<256, 256, 0, stream>>>(w3, b3, w4, b4, ws + WS_W34, ws + WS_B34);
    k_conv12<<<64 * 30, 256, 0, stream>>>(x, ws + WS_W12, ws + WS_B12, ws + WS_P1);
    k_conv34<<<640, 320, 0, stream>>>(ws + WS_P1, ws + WS_W34, ws + WS_B34,
                                      ws + WS_EMB);
    k_fc<<<128, 256, 0, stream>>>(ws + WS_EMB, w_ed1, b_ed1, w_ed2, b_ed2,
                                  w_ep1, b_ep1, w_ep2, b_ep2, esrc, edst,
                                  ws + WS_LOG);
    k_final<<<1, 64, 0, stream>>>(ws + WS_LOG, out);
}

// Round 3
// 594.118 us; speedup vs baseline: 1.4897x; 1.4897x over previous
//
#include <hip/hip_runtime.h>
#include <math.h>

// ---------------- workspace layout (floats) ----------------
#define WS_W12   0                         // [9*9][32]       = 2592
#define WS_B12   2592                      // 32
#define WS_W34   2624                      // [32][9][9][64]  = 165888
#define WS_B34   (2624 + 165888)           // 64
#define WS_P1    (WS_B34 + 64)             // [64][30][30][32] = 1843200 (ic innermost)
#define WS_EMB   (WS_P1 + 64*30*30*32)     // [64][1600]       = 102400

// ---------------- kernel A: compose both conv pairs -----------------------
// grid = 32 + 256: bid<32 -> conv1*conv2 (oc=bid); else conv3*conv4.
__global__ __launch_bounds__(256) void k_prep(
    const float* __restrict__ w1, const float* __restrict__ b1,
    const float* __restrict__ w2, const float* __restrict__ b2,
    const float* __restrict__ w3, const float* __restrict__ b3,
    const float* __restrict__ w4, const float* __restrict__ b4,
    float* __restrict__ W12, float* __restrict__ B12,
    float* __restrict__ W34, float* __restrict__ B34)
{
    int t = threadIdx.x;
    if (blockIdx.x < 32) {
        __shared__ float sW2[800];   // w2[oc][mc*25+e]
        __shared__ float sW1[800];   // w1[mc*25+e]
        int oc = blockIdx.x;
        for (int i = t; i < 800; i += 256) {
            sW2[i] = w2[oc * 800 + i];
            sW1[i] = w1[i];
        }
        __syncthreads();
        for (int uv = t; uv < 81; uv += 256) {
            int u = uv / 9, v = uv % 9;
            int ey0 = max(0, u - 4), ey1 = min(4, u);
            int ex0 = max(0, v - 4), ex1 = min(4, v);
            float s = 0.f;
            for (int mc = 0; mc < 32; ++mc) {
                const float* w2r = &sW2[mc * 25];
                const float* w1r = &sW1[mc * 25];
                for (int ey = ey0; ey <= ey1; ++ey)
                    for (int ex = ex0; ex <= ex1; ++ex)
                        s += w2r[ey * 5 + ex] * w1r[(u - ey) * 5 + (v - ex)];
            }
            W12[uv * 32 + oc] = s;
        }
        if (t == 0) {
            float s = b2[oc];
            for (int mc = 0; mc < 32; ++mc) {
                float ws = 0.f;
                for (int e = 0; e < 25; ++e) ws += sW2[mc * 25 + e];
                s += b1[mc] * ws;
            }
            B12[oc] = s;
        }
    } else {
        __shared__ float sW4[64 * 25];    // w4[oc][mc][e]
        __shared__ float sW3[64 * 200];   // w3[mc][icl][e]
        int bid = blockIdx.x - 32;
        int oc  = bid >> 2;
        int icg = bid & 3;
        for (int i = t; i < 1600; i += 256) sW4[i] = w4[oc * 1600 + i];
        for (int i = t; i < 64 * 200; i += 256) {
            int mc = i / 200, r = i % 200;
            sW3[i] = w3[mc * 800 + icg * 200 + r];
        }
        __syncthreads();
        for (int o = t; o < 648; o += 256) {
            int icl = o / 81;
            int uv  = o % 81;
            int u = uv / 9, v = uv % 9;
            int ey0 = max(0, u - 4), ey1 = min(4, u);
            int ex0 = max(0, v - 4), ex1 = min(4, v);
            float s = 0.f;
            for (int mc = 0; mc < 64; ++mc) {
                const float* w4r = &sW4[mc * 25];
                const float* w3r = &sW3[mc * 200 + icl * 25];
                for (int ey = ey0; ey <= ey1; ++ey)
                    for (int ex = ex0; ex <= ex1; ++ex)
                        s += w4r[ey * 5 + ex] * w3r[(u - ey) * 5 + (v - ex)];
            }
            int ic = icg * 8 + icl;
            W34[(ic * 81 + uv) * 64 + oc] = s;
        }
        if (icg == 0 && t == 0) {
            float s = b4[oc];
            for (int mc = 0; mc < 64; ++mc) {
                float ws = 0.f;
                for (int e = 0; e < 25; ++e) ws += sW4[mc * 25 + e];
                s += b3[mc] * ws;
            }
            B34[oc] = s;
        }
    }
}

// ---------------- kernel B: fused 9x9 conv12 + 4x4 maxpool ----------------
// grid = 64 batches * 30 pool-rows; block = 256 = 32 oc * 8 px-groups.
__global__ __launch_bounds__(256) void k_conv12(
    const float* __restrict__ x, const float* __restrict__ W12,
    const float* __restrict__ B12, float* __restrict__ P1)
{
    __shared__ float sIn[12][128];

    int b  = blockIdx.x / 30;
    int py = blockIdx.x % 30;
    int t  = threadIdx.x;

    const float* xb = x + b * 128 * 128;
    for (int i = t; i < 12 * 32; i += 256) {
        int row = i >> 5, c4 = i & 31;
        ((float4*)sIn[row])[c4] =
            ((const float4*)(xb + (4 * py + row) * 128))[c4];
    }

    int oc = t & 31;
    int pg = t >> 5;
    float w[81];
    #pragma unroll
    for (int e = 0; e < 81; ++e) w[e] = W12[e * 32 + oc];
    float bias = B12[oc];
    __syncthreads();

    for (int j = 0; j < 4; ++j) {
        int px = pg + 8 * j;
        if (px >= 30) break;
        float acc[4][4];
        #pragma unroll
        for (int iy = 0; iy < 4; ++iy)
            #pragma unroll
            for (int ix = 0; ix < 4; ++ix) acc[iy][ix] = 0.f;

        #pragma unroll
        for (int r = 0; r < 12; ++r) {
            const float* rp = sIn[r] + 4 * px;
            float4 A  = ((const float4*)rp)[0];
            float4 Bq = ((const float4*)rp)[1];
            float4 Cq = ((const float4*)rp)[2];
            float win[12] = {A.x, A.y, A.z, A.w, Bq.x, Bq.y, Bq.z, Bq.w,
                             Cq.x, Cq.y, Cq.z, Cq.w};
            #pragma unroll
            for (int iy = 0; iy < 4; ++iy) {
                int ky = r - iy;
                if (ky < 0 || ky > 8) continue;
                #pragma unroll
                for (int ix = 0; ix < 4; ++ix)
                    #pragma unroll
                    for (int kx = 0; kx < 9; ++kx)
                        acc[iy][ix] = fmaf(w[ky * 9 + kx], win[ix + kx],
                                           acc[iy][ix]);
            }
        }
        float m = -INFINITY;
        #pragma unroll
        for (int iy = 0; iy < 4; ++iy)
            #pragma unroll
            for (int ix = 0; ix < 4; ++ix) m = fmaxf(m, acc[iy][ix]);
        P1[((b * 30 + py) * 30 + px) * 32 + oc] = m + bias;
    }
}

// ---------------- kernel C: fused 9x9 conv34 + 4x4 maxpool ----------------
// grid = 64 b * 5 py * 2 oc-halves = 640; block = 320 = 32 ocl * 10 grp.
// sIn is [row][col][ic] so staging is coalesced global + conflict-free LDS;
// compute reads are uniform per half-wave (broadcast).
__global__ __launch_bounds__(320, 4) void k_conv34(
    const float* __restrict__ P1, const float* __restrict__ W34,
    const float* __restrict__ B34, float* __restrict__ emb)
{
    __shared__ float sIn[12][30][32];   // [row][col][ic] = 46080 B
    __shared__ float sPool[10][32];

    int bi  = blockIdx.x;
    int b   = bi / 10;
    int rem = bi % 10;
    int py  = rem >> 1;
    int oh  = rem & 1;
    int t   = threadIdx.x;

    // stage: 2880 float4; 8 lanes per (row,col) cover ic 0..31 -> 128B
    // contiguous in both global and LDS (conflict-free, coalesced)
    for (int i = t; i < 2880; i += 320) {
        int q   = i & 7;
        int rc  = i >> 3;                 // 0..359
        int row = rc / 30, col = rc % 30;
        ((float4*)&sIn[row][col][0])[q] =
            ((const float4*)(P1 + ((b * 30 + 4 * py + row) * 30 + col) * 32))[q];
    }
    __syncthreads();

    int ocl  = t & 31;
    int oc   = ocl + (oh << 5);
    int grp  = t >> 5;          // 0..9
    int iyh  = grp / 5;         // iy in {2iyh, 2iyh+1}
    int cgrp = grp % 5;         // pool col

    float acc[2][4];
    #pragma unroll
    for (int d = 0; d < 2; ++d)
        #pragma unroll
        for (int ix = 0; ix < 4; ++ix) acc[d][ix] = 0.f;

    for (int ic = 0; ic < 32; ++ic) {
        float w[81];
        #pragma unroll
        for (int e = 0; e < 81; ++e)      // coalesced burst, L2-resident
            w[e] = W34[(ic * 81 + e) * 64 + oc];

        #pragma unroll
        for (int ro = 0; ro < 10; ++ro) { // each (ic,row) window read ONCE
            int row = 2 * iyh + ro;
            float win[12];
            #pragma unroll
            for (int c = 0; c < 12; ++c) win[c] = sIn[row][4 * cgrp + c][ic];
            #pragma unroll
            for (int d = 0; d < 2; ++d) {
                int ky = ro - d;          // compile-time after unroll
                if (ky < 0 || ky > 8) continue;
                #pragma unroll
                for (int ix = 0; ix < 4; ++ix)
                    #pragma unroll
                    for (int kx = 0; kx < 9; ++kx)
                        acc[d][ix] = fmaf(w[ky * 9 + kx], win[ix + kx],
                                          acc[d][ix]);
            }
        }
    }

    float pmax = -INFINITY;
    #pragma unroll
    for (int d = 0; d < 2; ++d)
        #pragma unroll
        for (int ix = 0; ix < 4; ++ix) pmax = fmaxf(pmax, acc[d][ix]);
    sPool[grp][ocl] = pmax;
    __syncthreads();

    if (grp < 5) {
        float m = fmaxf(sPool[grp][ocl], sPool[grp + 5][ocl]) + B34[oc];
        emb[b * 1600 + oc * 25 + py * 5 + grp] = m;
    }
}

// ---------------- kernel D: both FC heads + sigmoid product --------------
__device__ __forceinline__ float block_sum256(float v, float* sred, int t) {
    #pragma unroll
    for (int o = 32; o; o >>= 1) v += __shfl_down(v, o, 64);
    if ((t & 63) == 0) sred[t >> 6] = v;
    __syncthreads();
    float r = sred[0] + sred[1] + sred[2] + sred[3];
    __syncthreads();
    return r;
}

// grid = 64 (one block per batch); block = 256 = hidden unit
__global__ __launch_bounds__(256) void k_fc(
    const float* __restrict__ emb,
    const float* __restrict__ w_ed1, const float* __restrict__ b_ed1,
    const float* __restrict__ w_ed2, const float* __restrict__ b_ed2,
    const float* __restrict__ w_ep1, const float* __restrict__ b_ep1,
    const float* __restrict__ w_ep2, const float* __restrict__ b_ep2,
    const int* __restrict__ esrc, const int* __restrict__ edst,
    float* __restrict__ out)
{
    __shared__ float se[1600];
    __shared__ float sred[4];

    int b = blockIdx.x;
    int j = threadIdx.x;

    for (int i = j; i < 1600; i += 256) se[i] = emb[b * 1600 + i];
    __syncthreads();

    float s_ed = b_ed1[j];
    for (int k = 0; k < 1600; ++k) s_ed = fmaf(se[k], w_ed1[k * 256 + j], s_ed);
    float h_ed = fmaxf(s_ed, 0.f);

    float s_ep = b_ep1[j];
    for (int k = 0; k < 1600; ++k) s_ep = fmaf(se[k], w_ep1[k * 256 + j], s_ep);
    float h_ep = fmaxf(s_ep, 0.f);

    int c0 = esrc[0];
    int c1 = edst[0];
    float te = block_sum256(h_ed * w_ed2[j * 120 + 0], sred, j);
    float t0 = block_sum256(h_ep * w_ep2[j * 36 + c0], sred, j);
    float t1 = block_sum256(h_ep * w_ep2[j * 36 + c1], sred, j);

    if (j == 0) {
        float le  = te + b_ed2[0];
        float l0  = t0 + b_ep2[c0];
        float l1  = t1 + b_ep2[c1];
        float se_  = 1.f / (1.f + expf(-le));
        float sp0 = 1.f / (1.f + expf(-l0));
        float sp1 = 1.f / (1.f + expf(-l1));
        out[b] = se_ * sp0 * sp1;
    }
}

// ---------------- launch --------------------------------------------------
extern "C" void kernel_launch(void* const* d_in, const int* in_sizes, int n_in,
                              void* d_out, int out_size, void* d_ws, size_t ws_size,
                              hipStream_t stream)
{
    const float* x     = (const float*)d_in[0];
    const float* w1    = (const float*)d_in[1];
    const float* b1    = (const float*)d_in[2];
    const float* w2    = (const float*)d_in[3];
    const float* b2    = (const float*)d_in[4];
    const float* w3    = (const float*)d_in[5];
    const float* b3    = (const float*)d_in[6];
    const float* w4    = (const float*)d_in[7];
    const float* b4    = (const float*)d_in[8];
    const float* w_ed1 = (const float*)d_in[9];
    const float* b_ed1 = (const float*)d_in[10];
    const float* w_ed2 = (const float*)d_in[11];
    const float* b_ed2 = (const float*)d_in[12];
    const float* w_ep1 = (const float*)d_in[13];
    const float* b_ep1 = (const float*)d_in[14];
    const float* w_ep2 = (const float*)d_in[15];
    const float* b_ep2 = (const float*)d_in[16];
    const int*   esrc  = (const int*)d_in[17];
    const int*   edst  = (const int*)d_in[18];

    float* ws  = (float*)d_ws;
    float* out = (float*)d_out;

    k_prep<<<288, 256, 0, stream>>>(w1, b1, w2, b2, w3, b3, w4, b4,
                                    ws + WS_W12, ws + WS_B12,
                                    ws + WS_W34, ws + WS_B34);
    k_conv12<<<64 * 30, 256, 0, stream>>>(x, ws + WS_W12, ws + WS_B12, ws + WS_P1);
    k_conv34<<<640, 320, 0, stream>>>(ws + WS_P1, ws + WS_W34, ws + WS_B34,
                                      ws + WS_EMB);
    k_fc<<<64, 256, 0, stream>>>(ws + WS_EMB, w_ed1, b_ed1, w_ed2, b_ed2,
                                 w_ep1, b_ep1, w_ep2, b_ep2, esrc, edst, out);
}

// Round 4
// 443.076 us; speedup vs baseline: 1.9975x; 1.3409x over previous
//
#include <hip/hip_runtime.h>
#include <math.h>

// ---------------- workspace layout (floats) ----------------
#define WS_W12   0                         // [9*9][32]        = 2592
#define WS_B12   2592                      // 32
#define WS_W34   2624                      // [32*81][64]      = 165888
#define WS_B34   (2624 + 165888)           // 64
#define WS_P1    (WS_B34 + 64)             // [64][30][30][32] = 1843200
#define WS_EMBT  (WS_P1 + 64*30*30*32)     // [1600][64]       = 102400
#define WS_HID   WS_P1                     // [2*256][64] = 32768 (P1 dead by then)

// ---------------- kernel A: compose both conv pairs -----------------------
// grid = 32 + 512 blocks, 384 threads.
//  bid<32: conv1*conv2, oc=bid.
//  else:   conv3*conv4, (bid-32) = oc*8 + icq, icq -> 4 ic values.
__global__ __launch_bounds__(384) void k_prep(
    const float* __restrict__ w1, const float* __restrict__ b1,
    const float* __restrict__ w2, const float* __restrict__ b2,
    const float* __restrict__ w3, const float* __restrict__ b3,
    const float* __restrict__ w4, const float* __restrict__ b4,
    float* __restrict__ W12, float* __restrict__ B12,
    float* __restrict__ W34, float* __restrict__ B34)
{
    __shared__ float smem[8448];            // 33.8 KB
    int t = threadIdx.x;

    if (blockIdx.x < 32) {
        // ---------------- prep12 ----------------
        float* sW2 = smem;                  // [mc*25+e]
        float* sW1 = smem + 800;
        int oc = blockIdx.x;
        for (int i = t; i < 800; i += 384) {
            sW2[i] = w2[oc * 800 + i];
            sW1[i] = w1[i];
        }
        __syncthreads();
        if (t < 81) {
            int u = t / 9, v = t % 9;
            float acc[4] = {0.f, 0.f, 0.f, 0.f};
            #pragma unroll
            for (int e = 0; e < 25; ++e) {
                int ey = e / 5, ex = e % 5;
                int du = u - ey, dv = v - ex;
                if ((unsigned)du <= 4u && (unsigned)dv <= 4u) {
                    int ep = du * 5 + dv;
                    for (int mc = 0; mc < 32; ++mc)
                        acc[e & 3] = fmaf(sW2[mc * 25 + e], sW1[mc * 25 + ep],
                                          acc[e & 3]);
                }
            }
            W12[t * 32 + oc] = (acc[0] + acc[1]) + (acc[2] + acc[3]);
        }
        if (t < 32) {
            float ws = 0.f;
            #pragma unroll
            for (int e = 0; e < 25; ++e) ws += sW2[t * 25 + e];
            float p = b1[t] * ws;
            #pragma unroll
            for (int off = 16; off; off >>= 1) p += __shfl_down(p, off, 64);
            if (t == 0) B12[oc] = p + b2[oc];
        }
    } else {
        // ---------------- prep34 ----------------
        float* sW4  = smem;                 // [mc][28] (25 used, 16B-aligned rows)
        float* sW3R = smem + 1792;          // [mc][104] = [mc][icl*26 + e'], e'=25 is zeros
        int bid = blockIdx.x - 32;
        int oc  = bid >> 3;
        int icq = bid & 7;
        int icbase = icq * 4;

        for (int i = t; i < 1600; i += 384) {
            int mc = i / 25, e = i % 25;
            sW4[mc * 28 + e] = w4[oc * 1600 + i];        // coalesced
        }
        for (int i = t; i < 6400; i += 384) {
            int mc = i / 100, r = i % 100;
            int icl = r / 25, ep = r % 25;
            sW3R[mc * 104 + icl * 26 + ep] =
                w3[mc * 800 + (icbase + icl) * 25 + ep]; // runs of 100 contiguous
        }
        for (int i = t; i < 256; i += 384) {             // zero slots
            int icl = i >> 6, mc = i & 63;
            sW3R[mc * 104 + icl * 26 + 25] = 0.f;
        }
        __syncthreads();

        if (t < 324) {
            int icl = t / 81;
            int uv  = t % 81;
            int u = uv / 9, v = uv % 9;

            int ubase[25];
            #pragma unroll
            for (int e = 0; e < 25; ++e) {
                int ey = e / 5, ex = e % 5;
                int du = u - ey, dv = v - ex;
                bool ok = ((unsigned)du <= 4u) && ((unsigned)dv <= 4u);
                ubase[e] = icl * 26 + (ok ? du * 5 + dv : 25);
            }

            float acc[4] = {0.f, 0.f, 0.f, 0.f};
            #pragma unroll 8
            for (int mc = 0; mc < 64; ++mc) {
                const float* wrow = &sW4[mc * 28];
                float4 q0 = ((const float4*)wrow)[0];
                float4 q1 = ((const float4*)wrow)[1];
                float4 q2 = ((const float4*)wrow)[2];
                float4 q3 = ((const float4*)wrow)[3];
                float4 q4 = ((const float4*)wrow)[4];
                float4 q5 = ((const float4*)wrow)[5];
                float w4s[25] = {q0.x,q0.y,q0.z,q0.w, q1.x,q1.y,q1.z,q1.w,
                                 q2.x,q2.y,q2.z,q2.w, q3.x,q3.y,q3.z,q3.w,
                                 q4.x,q4.y,q4.z,q4.w, q5.x,q5.y,q5.z,q5.w,
                                 wrow[24]};
                const float* r3 = &sW3R[mc * 104];
                #pragma unroll
                for (int e = 0; e < 25; ++e)
                    acc[e & 3] = fmaf(w4s[e], r3[ubase[e]], acc[e & 3]);
            }
            int ic = icbase + icl;
            W34[(ic * 81 + uv) * 64 + oc] =
                (acc[0] + acc[1]) + (acc[2] + acc[3]);
        }

        if (icq == 0 && t < 64) {
            float ws = 0.f;
            #pragma unroll
            for (int e = 0; e < 25; ++e) ws += sW4[t * 28 + e];
            float p = b3[t] * ws;
            #pragma unroll
            for (int off = 32; off; off >>= 1) p += __shfl_down(p, off, 64);
            if (t == 0) B34[oc] = p + b4[oc];
        }
    }
}

// ---------------- kernel B: fused 9x9 conv12 + 4x4 maxpool ----------------
// grid = 64 batches * 30 pool-rows; block = 256 = 32 oc * 8 px-groups.
__global__ __launch_bounds__(256) void k_conv12(
    const float* __restrict__ x, const float* __restrict__ W12,
    const float* __restrict__ B12, float* __restrict__ P1)
{
    __shared__ float sIn[12][128];

    int b  = blockIdx.x / 30;
    int py = blockIdx.x % 30;
    int t  = threadIdx.x;

    const float* xb = x + b * 128 * 128;
    for (int i = t; i < 12 * 32; i += 256) {
        int row = i >> 5, c4 = i & 31;
        ((float4*)sIn[row])[c4] =
            ((const float4*)(xb + (4 * py + row) * 128))[c4];
    }

    int oc = t & 31;
    int pg = t >> 5;
    float w[81];
    #pragma unroll
    for (int e = 0; e < 81; ++e) w[e] = W12[e * 32 + oc];
    float bias = B12[oc];
    __syncthreads();

    for (int j = 0; j < 4; ++j) {
        int px = pg + 8 * j;
        if (px >= 30) break;
        float acc[4][4];
        #pragma unroll
        for (int iy = 0; iy < 4; ++iy)
            #pragma unroll
            for (int ix = 0; ix < 4; ++ix) acc[iy][ix] = 0.f;

        #pragma unroll
        for (int r = 0; r < 12; ++r) {
            const float* rp = sIn[r] + 4 * px;
            float4 A  = ((const float4*)rp)[0];
            float4 Bq = ((const float4*)rp)[1];
            float4 Cq = ((const float4*)rp)[2];
            float win[12] = {A.x, A.y, A.z, A.w, Bq.x, Bq.y, Bq.z, Bq.w,
                             Cq.x, Cq.y, Cq.z, Cq.w};
            #pragma unroll
            for (int iy = 0; iy < 4; ++iy) {
                int ky = r - iy;
                if (ky < 0 || ky > 8) continue;
                #pragma unroll
                for (int ix = 0; ix < 4; ++ix)
                    #pragma unroll
                    for (int kx = 0; kx < 9; ++kx)
                        acc[iy][ix] = fmaf(w[ky * 9 + kx], win[ix + kx],
                                           acc[iy][ix]);
            }
        }
        float m = -INFINITY;
        #pragma unroll
        for (int iy = 0; iy < 4; ++iy)
            #pragma unroll
            for (int ix = 0; ix < 4; ++ix) m = fmaxf(m, acc[iy][ix]);
        P1[((b * 30 + py) * 30 + px) * 32 + oc] = m + bias;
    }
}

// ---------------- kernel C: fused 9x9 conv34 + 4x4 maxpool ----------------
// grid = 64 b * 5 py * 2 oc-halves = 640; block = 320 = 32 ocl * 10 grp.
__global__ __launch_bounds__(320, 4) void k_conv34(
    const float* __restrict__ P1, const float* __restrict__ W34,
    const float* __restrict__ B34, float* __restrict__ embT)
{
    __shared__ float sIn[12][30][32];   // [row][col][ic]
    __shared__ float sPool[10][32];

    int bi  = blockIdx.x;
    int b   = bi / 10;
    int rem = bi % 10;
    int py  = rem >> 1;
    int oh  = rem & 1;
    int t   = threadIdx.x;

    for (int i = t; i < 2880; i += 320) {
        int q   = i & 7;
        int rc  = i >> 3;
        int row = rc / 30, col = rc % 30;
        ((float4*)&sIn[row][col][0])[q] =
            ((const float4*)(P1 + ((b * 30 + 4 * py + row) * 30 + col) * 32))[q];
    }
    __syncthreads();

    int ocl  = t & 31;
    int oc   = ocl + (oh << 5);
    int grp  = t >> 5;
    int iyh  = grp / 5;
    int cgrp = grp % 5;

    float acc[2][4];
    #pragma unroll
    for (int d = 0; d < 2; ++d)
        #pragma unroll
        for (int ix = 0; ix < 4; ++ix) acc[d][ix] = 0.f;

    for (int ic = 0; ic < 32; ++ic) {
        float w[81];
        #pragma unroll
        for (int e = 0; e < 81; ++e)
            w[e] = W34[(ic * 81 + e) * 64 + oc];

        #pragma unroll
        for (int ro = 0; ro < 10; ++ro) {
            int row = 2 * iyh + ro;
            float win[12];
            #pragma unroll
            for (int c = 0; c < 12; ++c) win[c] = sIn[row][4 * cgrp + c][ic];
            #pragma unroll
            for (int d = 0; d < 2; ++d) {
                int ky = ro - d;
                if (ky < 0 || ky > 8) continue;
                #pragma unroll
                for (int ix = 0; ix < 4; ++ix)
                    #pragma unroll
                    for (int kx = 0; kx < 9; ++kx)
                        acc[d][ix] = fmaf(w[ky * 9 + kx], win[ix + kx],
                                          acc[d][ix]);
            }
        }
    }

    float pmax = -INFINITY;
    #pragma unroll
    for (int d = 0; d < 2; ++d)
        #pragma unroll
        for (int ix = 0; ix < 4; ++ix) pmax = fmaxf(pmax, acc[d][ix]);
    sPool[grp][ocl] = pmax;
    __syncthreads();

    if (grp < 5) {
        float m = fmaxf(sPool[grp][ocl], sPool[grp + 5][ocl]) + B34[oc];
        embT[(oc * 25 + py * 5 + grp) * 64 + b] = m;   // transposed [k][b]
    }
}

// ---------------- kernel D1: first FC layer, both heads -------------------
// grid = 128: head = bid>>6, jg = bid&63 (4 hidden units). block 256:
// b = t&63 (coalesced embT), jl = t>>6 (wave-uniform -> W1 broadcast).
__global__ __launch_bounds__(256) void k_fc1(
    const float* __restrict__ embT,
    const float* __restrict__ w_ed1, const float* __restrict__ b_ed1,
    const float* __restrict__ w_ep1, const float* __restrict__ b_ep1,
    float* __restrict__ hid)
{
    int head = blockIdx.x >> 6;
    int jg   = blockIdx.x & 63;
    int b    = threadIdx.x & 63;
    int jl   = __builtin_amdgcn_readfirstlane(threadIdx.x >> 6);
    int j    = jg * 4 + jl;

    const float* W1 = head ? w_ep1 : w_ed1;
    float s = head ? b_ep1[j] : b_ed1[j];
    #pragma unroll 8
    for (int k = 0; k < 1600; ++k)
        s = fmaf(embT[k * 64 + b], W1[k * 256 + j], s);
    hid[(head * 256 + j) * 64 + b] = fmaxf(s, 0.f);
}

// ---------------- kernel D2: second FC layer (3 cols) + sigmoid product ---
__global__ __launch_bounds__(256) void k_fc2(
    const float* __restrict__ hid,
    const float* __restrict__ w_ed2, const float* __restrict__ b_ed2,
    const float* __restrict__ w_ep2, const float* __restrict__ b_ep2,
    const int* __restrict__ esrc, const int* __restrict__ edst,
    float* __restrict__ out)
{
    __shared__ float sl[192];
    int t = threadIdx.x;
    if (t < 192) {
        int q = __builtin_amdgcn_readfirstlane(t >> 6);   // 0,1,2
        int b = t & 63;
        int c0 = esrc[0], c1 = edst[0];
        int head = (q > 0) ? 1 : 0;
        float acc = 0.f;
        #pragma unroll 4
        for (int j = 0; j < 256; ++j) {
            float w = (q == 0) ? w_ed2[j * 120]
                    : (q == 1) ? w_ep2[j * 36 + c0]
                               : w_ep2[j * 36 + c1];
            acc = fmaf(hid[(head * 256 + j) * 64 + b], w, acc);
        }
        float bias = (q == 0) ? b_ed2[0] : (q == 1) ? b_ep2[c0] : b_ep2[c1];
        float logit = acc + bias;
        sl[q * 64 + b] = 1.f / (1.f + expf(-logit));
    }
    __syncthreads();
    if (t < 64) out[t] = sl[t] * sl[64 + t] * sl[128 + t];
}

// ---------------- launch --------------------------------------------------
extern "C" void kernel_launch(void* const* d_in, const int* in_sizes, int n_in,
                              void* d_out, int out_size, void* d_ws, size_t ws_size,
                              hipStream_t stream)
{
    const float* x     = (const float*)d_in[0];
    const float* w1    = (const float*)d_in[1];
    const float* b1    = (const float*)d_in[2];
    const float* w2    = (const float*)d_in[3];
    const float* b2    = (const float*)d_in[4];
    const float* w3    = (const float*)d_in[5];
    const float* b3    = (const float*)d_in[6];
    const float* w4    = (const float*)d_in[7];
    const float* b4    = (const float*)d_in[8];
    const float* w_ed1 = (const float*)d_in[9];
    const float* b_ed1 = (const float*)d_in[10];
    const float* w_ed2 = (const float*)d_in[11];
    const float* b_ed2 = (const float*)d_in[12];
    const float* w_ep1 = (const float*)d_in[13];
    const float* b_ep1 = (const float*)d_in[14];
    const float* w_ep2 = (const float*)d_in[15];
    const float* b_ep2 = (const float*)d_in[16];
    const int*   esrc  = (const int*)d_in[17];
    const int*   edst  = (const int*)d_in[18];

    float* ws  = (float*)d_ws;
    float* out = (float*)d_out;

    k_prep<<<544, 384, 0, stream>>>(w1, b1, w2, b2, w3, b3, w4, b4,
                                    ws + WS_W12, ws + WS_B12,
                                    ws + WS_W34, ws + WS_B34);
    k_conv12<<<64 * 30, 256, 0, stream>>>(x, ws + WS_W12, ws + WS_B12, ws + WS_P1);
    k_conv34<<<640, 320, 0, stream>>>(ws + WS_P1, ws + WS_W34, ws + WS_B34,
                                      ws + WS_EMBT);
    k_fc1<<<128, 256, 0, stream>>>(ws + WS_EMBT, w_ed1, b_ed1, w_ep1, b_ep1,
                                   ws + WS_HID);
    k_fc2<<<1, 256, 0, stream>>>(ws + WS_HID, w_ed2, b_ed2, w_ep2, b_ep2,
                                 esrc, edst, out);
}